// Round 3
// baseline (362.698 us; speedup 1.0000x reference)
//
#include <hip/hip_runtime.h>

#define NPTS   20000
#define NCHUNK 313   // ceil(NPTS/64)

typedef __bf16 bf16x8 __attribute__((ext_vector_type(8)));
typedef float  f32x4  __attribute__((ext_vector_type(4)));

__device__ __forceinline__ unsigned short f2b(float f) {
    union { float f; unsigned int i; } v; v.f = f;
    unsigned int u = v.i;
    return (unsigned short)((u + 0x7FFFu + ((u >> 16) & 1u)) >> 16);  // RNE
}

__device__ __forceinline__ bf16x8 pack8(const float* __restrict__ f) {
    union { unsigned short s[8]; bf16x8 v; } u;
    #pragma unroll
    for (int i = 0; i < 8; ++i) u.s[i] = f2b(f[i]);
    return u.v;
}

struct __align__(16) SMem {
    union {
        unsigned long long bitmap[4][320];          // 10240 B (stages A/B)
        struct {
            unsigned short h1[64][72];              // 9216 B  [sample][ch], +8 pad
            unsigned short h2[64][136];             // 17408 B [sample][ch], +8 pad
        } c;                                        // (stage C)
    } u;
    float  X[4][64][3];
    int    idx[4][64];
    float2 sb1[64];
    float2 sb2[128];
    float2 sb3[256];
};

__global__ __launch_bounds__(256, 2)
void cloudcrop_kernel(const float* __restrict__ seed_xyz,
                      const float* __restrict__ pointcloud,
                      const float* __restrict__ vp_rot,
                      const float* __restrict__ w1,
                      const float* __restrict__ g1,  const float* __restrict__ be1,
                      const float* __restrict__ mn1, const float* __restrict__ vr1,
                      const float* __restrict__ w2,
                      const float* __restrict__ g2,  const float* __restrict__ be2,
                      const float* __restrict__ mn2, const float* __restrict__ vr2,
                      const float* __restrict__ w3,
                      const float* __restrict__ g3,  const float* __restrict__ be3,
                      const float* __restrict__ mn3, const float* __restrict__ vr3,
                      float* __restrict__ out)
{
    __shared__ SMem sm;
    const int tid = threadIdx.x;
    const int wv  = tid >> 6;     // wave 0..3
    const int ln  = tid & 63;     // lane
    const int q   = ln >> 4;      // quad
    const int l15 = ln & 15;
    const int bs  = blockIdx.x;   // b*1024 + s
    const int b   = bs >> 10;
    const int s   = bs & 1023;

    // ---- BN scale/bias precompute into LDS (fp32) ----
    {
        float inv = g3[tid] / sqrtf(vr3[tid] + 1e-5f);
        sm.sb3[tid] = make_float2(inv, be3[tid] - mn3[tid] * inv);
    }
    if (tid < 128) {
        float inv = g2[tid] / sqrtf(vr2[tid] + 1e-5f);
        sm.sb2[tid] = make_float2(inv, be2[tid] - mn2[tid] * inv);
    }
    if (tid < 64) {
        float inv = g1[tid] / sqrtf(vr1[tid] + 1e-5f);
        sm.sb1[tid] = make_float2(inv, be1[tid] - mn1[tid] * inv);
    }

    // ---- per-seed constants ----
    const float sx = seed_xyz[bs*3+0];
    const float sy = seed_xyz[bs*3+1];
    const float sz = seed_xyz[bs*3+2];
    const float R00 = vp_rot[bs*9+0], R01 = vp_rot[bs*9+1], R02 = vp_rot[bs*9+2];
    const float R10 = vp_rot[bs*9+3], R11 = vp_rot[bs*9+4], R12 = vp_rot[bs*9+5];
    const float R20 = vp_rot[bs*9+6], R21 = vp_rot[bs*9+7], R22 = vp_rot[bs*9+8];

    // ---- weight A-fragments, fp32 -> bf16 (registers, reused for all 4 d-groups) ----
    // A layout: A[m = lane&15][k = quad*8 + j], 8 bf16 per lane
    bf16x8 aw2[2][2], aw3[4][4];
    #pragma unroll
    for (int m = 0; m < 2; ++m)
        #pragma unroll
        for (int kk = 0; kk < 2; ++kk)
            aw2[m][kk] = pack8(w2 + ((wv*2+m)*16 + l15)*64 + kk*32 + q*8);
    #pragma unroll
    for (int m = 0; m < 4; ++m)
        #pragma unroll
        for (int kk = 0; kk < 4; ++kk)
            aw3[m][kk] = pack8(w3 + ((wv*4+m)*16 + l15)*128 + kk*32 + q*8);

    // ---- stage A: cylinder-mask scan -> bitmaps (wave wv takes chunks c%4==wv) ----
    {
        #pragma clang fp contract(off)
        for (int c = wv; c < NCHUNK; c += 4) {
            int n = c*64 + ln;
            bool valid = (n < NPTS);
            int nc = valid ? n : (NPTS - 1);
            const float* p = pointcloud + (b*NPTS + nc)*3;
            float rx = p[0] - sx;
            float ry = p[1] - sy;
            float rz = p[2] - sz;
            float x = (rx*R00 + ry*R10) + rz*R20;
            float y = (rx*R01 + ry*R11) + rz*R21;
            float z = (rx*R02 + ry*R12) + rz*R22;
            bool mb = ((y*y + z*z) < 0.0025f) && (x > -0.02f) && valid;
            unsigned long long m0 = __ballot(mb && (x < 0.01f));
            unsigned long long m1 = __ballot(mb && (x < 0.02f));
            unsigned long long m2 = __ballot(mb && (x < 0.03f));
            unsigned long long m3 = __ballot(mb && (x < 0.04f));
            if (ln == 0) {
                sm.u.bitmap[0][c] = m0;
                sm.u.bitmap[1][c] = m1;
                sm.u.bitmap[2][c] = m2;
                sm.u.bitmap[3][c] = m3;
            }
        }
    }
    __syncthreads();

    // ---- stage B: ordered first-64 extraction per d (wave wv handles d=wv) ----
    {
        const int d = wv;
        int carry = 0;
        for (int r = 0; r < 5 && carry < 64; ++r) {
            int c = r*64 + ln;
            unsigned long long w = (c < NCHUNK) ? sm.u.bitmap[d][c] : 0ULL;
            int wc = __popcll(w);
            int incl = wc;                          // wave prefix-sum (word order == lane order)
            #pragma unroll
            for (int off = 1; off < 64; off <<= 1) {
                int t = __shfl_up(incl, off);
                if (ln >= off) incl += t;
            }
            int rank  = carry + incl - wc;          // exclusive prefix
            int total = __shfl(incl, 63);
            while (w && rank < 64) {
                int bp = __builtin_ctzll(w);
                w &= w - 1;
                sm.idx[d][rank] = c*64 + bp;
                ++rank;
            }
            carry += total;
        }
        int cnt = carry < 64 ? carry : 64;
        int first = (cnt > 0) ? sm.idx[d][0] : 0;   // ref: pad with idx[0], or 0 if no hit
        if (ln >= cnt) sm.idx[d][ln] = first;
    }
    __syncthreads();

    // ---- gather: recompute rel_rot (fp32, contract off) for the 4*64 selected points ----
    {
        #pragma clang fp contract(off)
        int n = sm.idx[wv][ln];
        const float* p = pointcloud + (b*NPTS + n)*3;
        float rx = p[0] - sx;
        float ry = p[1] - sy;
        float rz = p[2] - sz;
        sm.X[wv][ln][0] = (rx*R00 + ry*R10) + rz*R20;
        sm.X[wv][ln][1] = (rx*R01 + ry*R11) + rz*R21;
        sm.X[wv][ln][2] = (rx*R02 + ry*R12) + rz*R22;
    }
    __syncthreads();

    // ---- stage C: MLP + max, one d-group (64 samples) at a time ----
    for (int d = 0; d < 4; ++d) {
        // layer 1 (K=3, VALU, fp32): thread -> sample ln, channels wv*16..+15
        {
            float x0 = sm.X[d][ln][0];
            float x1 = sm.X[d][ln][1];
            float x2 = sm.X[d][ln][2];
            unsigned int pk[8];
            #pragma unroll
            for (int i = 0; i < 8; ++i) {
                unsigned short hv[2];
                #pragma unroll
                for (int t = 0; t < 2; ++t) {
                    int ch = wv*16 + i*2 + t;
                    float h = x0*w1[ch*3+0] + x1*w1[ch*3+1] + x2*w1[ch*3+2];
                    float2 sb = sm.sb1[ch];
                    hv[t] = f2b(fmaxf(fmaf(h, sb.x, sb.y), 0.f));
                }
                pk[i] = (unsigned int)hv[0] | ((unsigned int)hv[1] << 16);
            }
            uint4 u0 = make_uint4(pk[0], pk[1], pk[2], pk[3]);
            uint4 u1 = make_uint4(pk[4], pk[5], pk[6], pk[7]);
            *(uint4*)&sm.u.c.h1[ln][wv*16 + 0] = u0;
            *(uint4*)&sm.u.c.h1[ln][wv*16 + 8] = u1;
        }
        __syncthreads();

        // layer 2: M=128 (wave owns 2 M-tiles), K=64, N=64
        #pragma unroll
        for (int nt = 0; nt < 4; ++nt) {
            int n = nt*16 + l15;
            // B layout: B[k = quad*8+j][n = lane&15] -> one ds_read_b128 per k-step
            bf16x8 b0 = *(const bf16x8*)&sm.u.c.h1[n][q*8];
            bf16x8 b1 = *(const bf16x8*)&sm.u.c.h1[n][32 + q*8];
            #pragma unroll
            for (int m = 0; m < 2; ++m) {
                f32x4 acc = {0.f, 0.f, 0.f, 0.f};
                acc = __builtin_amdgcn_mfma_f32_16x16x32_bf16(aw2[m][0], b0, acc, 0, 0, 0);
                acc = __builtin_amdgcn_mfma_f32_16x16x32_bf16(aw2[m][1], b1, acc, 0, 0, 0);
                // D: row(=out ch) = q*4+r, col(=sample) = l15
                int ch0 = (wv*2+m)*16 + q*4;
                unsigned short hh[4];
                #pragma unroll
                for (int r = 0; r < 4; ++r) {
                    float2 sb = sm.sb2[ch0 + r];
                    hh[r] = f2b(fmaxf(fmaf(acc[r], sb.x, sb.y), 0.f));
                }
                uint2 pkk;
                pkk.x = (unsigned int)hh[0] | ((unsigned int)hh[1] << 16);
                pkk.y = (unsigned int)hh[2] | ((unsigned int)hh[3] << 16);
                *(uint2*)&sm.u.c.h2[n][ch0] = pkk;
            }
        }
        __syncthreads();

        // layer 3: M=256 (wave owns 4 M-tiles), K=128, N=64, fused BN+ReLU+max
        {
            float rm[4][4];
            #pragma unroll
            for (int m = 0; m < 4; ++m)
                #pragma unroll
                for (int r = 0; r < 4; ++r) rm[m][r] = 0.f;   // post-ReLU values are >= 0

            #pragma unroll
            for (int nt = 0; nt < 4; ++nt) {
                int n = nt*16 + l15;
                bf16x8 bb0 = *(const bf16x8*)&sm.u.c.h2[n][ 0 + q*8];
                bf16x8 bb1 = *(const bf16x8*)&sm.u.c.h2[n][32 + q*8];
                bf16x8 bb2 = *(const bf16x8*)&sm.u.c.h2[n][64 + q*8];
                bf16x8 bb3 = *(const bf16x8*)&sm.u.c.h2[n][96 + q*8];
                #pragma unroll
                for (int m = 0; m < 4; ++m) {
                    f32x4 acc = {0.f, 0.f, 0.f, 0.f};
                    acc = __builtin_amdgcn_mfma_f32_16x16x32_bf16(aw3[m][0], bb0, acc, 0, 0, 0);
                    acc = __builtin_amdgcn_mfma_f32_16x16x32_bf16(aw3[m][1], bb1, acc, 0, 0, 0);
                    acc = __builtin_amdgcn_mfma_f32_16x16x32_bf16(aw3[m][2], bb2, acc, 0, 0, 0);
                    acc = __builtin_amdgcn_mfma_f32_16x16x32_bf16(aw3[m][3], bb3, acc, 0, 0, 0);
                    int ch0 = (wv*4+m)*16 + q*4;
                    #pragma unroll
                    for (int r = 0; r < 4; ++r) {
                        float2 sb = sm.sb3[ch0 + r];
                        float v = fmaxf(fmaf(acc[r], sb.x, sb.y), 0.f);  // BN before max (scale may be <0)
                        rm[m][r] = fmaxf(rm[m][r], v);
                    }
                }
            }
            // max over the 16 sample-columns: butterfly over lane bits 0..3
            #pragma unroll
            for (int m = 0; m < 4; ++m) {
                #pragma unroll
                for (int r = 0; r < 4; ++r) {
                    float v = rm[m][r];
                    v = fmaxf(v, __shfl_xor(v, 1));
                    v = fmaxf(v, __shfl_xor(v, 2));
                    v = fmaxf(v, __shfl_xor(v, 4));
                    v = fmaxf(v, __shfl_xor(v, 8));
                    if (l15 == 0) {
                        int ch = (wv*4+m)*16 + q*4 + r;
                        out[((b*256 + ch)*1024 + s)*4 + d] = v;   // fp32 output
                    }
                }
            }
        }
        __syncthreads();
    }
}

extern "C" void kernel_launch(void* const* d_in, const int* in_sizes, int n_in,
                              void* d_out, int out_size, void* d_ws, size_t ws_size,
                              hipStream_t stream) {
    (void)in_sizes; (void)n_in; (void)out_size; (void)d_ws; (void)ws_size;
    const float* seed = (const float*)d_in[0];
    const float* pc   = (const float*)d_in[1];
    const float* rot  = (const float*)d_in[2];
    const float* w1   = (const float*)d_in[3];
    const float* g1   = (const float*)d_in[4];
    const float* be1  = (const float*)d_in[5];
    const float* mn1  = (const float*)d_in[6];
    const float* vr1  = (const float*)d_in[7];
    const float* w2   = (const float*)d_in[8];
    const float* g2   = (const float*)d_in[9];
    const float* be2  = (const float*)d_in[10];
    const float* mn2  = (const float*)d_in[11];
    const float* vr2  = (const float*)d_in[12];
    const float* w3   = (const float*)d_in[13];
    const float* g3   = (const float*)d_in[14];
    const float* be3  = (const float*)d_in[15];
    const float* mn3  = (const float*)d_in[16];
    const float* vr3  = (const float*)d_in[17];

    cloudcrop_kernel<<<dim3(2048), dim3(256), 0, stream>>>(
        seed, pc, rot,
        w1, g1, be1, mn1, vr1,
        w2, g2, be2, mn2, vr2,
        w3, g3, be3, mn3, vr3,
        (float*)d_out);
}